// Round 19
// baseline (968.751 us; speedup 1.0000x reference)
//
#include <hip/hip_runtime.h>
#include <stdint.h>

#define NTOK 8192
#define H_ 1024
#define F_ 4096
#define E_ 8
#define VCAP 18432      // 16384 slots + up to 8*256 padding (virtual rows)
#define VMBLK 72        // VCAP/256 M-tiles (BM=256)
#define NCOMP 16384     // compact rows (= NTOK * k exactly)

using f32x4  = __attribute__((ext_vector_type(4))) float;
using short8 = __attribute__((ext_vector_type(8))) short;

typedef __attribute__((address_space(1))) const uint32_t gu32;
typedef __attribute__((address_space(3))) uint32_t lu32;

__device__ __forceinline__ void glds16(const void* g, void* l) {
  __builtin_amdgcn_global_load_lds((gu32*)g, (lu32*)l, 16, 0, 0);
}

__device__ __forceinline__ ushort f2bf(float f) {
  union { float f; uint32_t u; } v; v.f = f;
  uint32_t r = (v.u + 0x7FFFu + ((v.u >> 16) & 1u)) >> 16;
  return (ushort)r;
}

__device__ __forceinline__ float gelu_t(float x) {
  float u = 0.7978845608028654f * (x + 0.044715f * x * x * x);
  float e = exp2f(u * 2.885390081777927f);      // exp(2u)
  float th = 1.0f - 2.0f / (1.0f + e);
  return 0.5f * x * (1.0f + th);
}

// ---- wide transpose: 64-row x 256-col region, reads hoisted, fp32->bf16 ----
__device__ __forceinline__ void transcvt_tile4(const float* __restrict__ W,
                                               ushort* __restrict__ WT,
                                               int R, int C, int t4,
                                               float (*tb)[65]) {
  int nxw = C >> 8;
  int per_e = (R >> 6) * nxw;
  int e = t4 / per_e, rem = t4 % per_e;
  int r0 = (rem / nxw) << 6, c0 = (rem % nxw) << 8;
  const float* Wp = W + (size_t)e * R * C;
  ushort* Tp = WT + (size_t)e * R * C;
  int tx = threadIdx.x & 15, ty = threadIdx.x >> 4;

  float4 v[4][4];
#pragma unroll
  for (int p = 0; p < 4; p++)
#pragma unroll
    for (int i = 0; i < 4; i++) {
      int lr = ty + i * 16;
      v[p][i] = *(const float4*)&Wp[(size_t)(r0 + lr) * C + c0 + p * 64 + tx * 4];
    }
#pragma unroll
  for (int p = 0; p < 4; p++) {
    __syncthreads();
#pragma unroll
    for (int i = 0; i < 4; i++) {
      int lr = ty + i * 16;
      tb[lr][tx * 4 + 0] = v[p][i].x; tb[lr][tx * 4 + 1] = v[p][i].y;
      tb[lr][tx * 4 + 2] = v[p][i].z; tb[lr][tx * 4 + 3] = v[p][i].w;
    }
    __syncthreads();
#pragma unroll
    for (int i = 0; i < 4; i++) {
      int lc = ty + i * 16;
      ushort4 o;
      o.x = f2bf(tb[tx * 4 + 0][lc]);
      o.y = f2bf(tb[tx * 4 + 1][lc]);
      o.z = f2bf(tb[tx * 4 + 2][lc]);
      o.w = f2bf(tb[tx * 4 + 3][lc]);
      *(ushort4*)&Tp[(size_t)(c0 + p * 64 + lc) * R + r0 + tx * 4] = o;
    }
  }
}

// ---- prep2: router [0,2048) + W1T [2048,4096) + W2T [4096,6144) ------------
__global__ __launch_bounds__(256) void k_prep2(const float* __restrict__ W1,
                                               ushort* __restrict__ W1T,
                                               const float* __restrict__ W2,
                                               ushort* __restrict__ W2T,
                                               const float* __restrict__ x,
                                               const float* __restrict__ Wr,
                                               const float* __restrict__ br,
                                               const float* __restrict__ bbuf,
                                               int* cnt, int* te, float* tw,
                                               int* tok, float* wl, int* v2c) {
  __shared__ float tb[64][65];
  int bid = blockIdx.x;
  if (bid < 2048) {                       // ---- router path ----
    int wid = threadIdx.x >> 6, lane = threadIdx.x & 63;
    int t = bid * 4 + wid;
    const float* xp = x + (size_t)t * H_;
    double acc[E_];
#pragma unroll
    for (int e = 0; e < E_; e++) acc[e] = 0.0;
    for (int j = lane; j < H_; j += 64) {
      float xv = xp[j];
      const float4 w0 = *(const float4*)&Wr[j * 8];
      const float4 w1 = *(const float4*)&Wr[j * 8 + 4];
      acc[0] += (double)xv * (double)w0.x;
      acc[1] += (double)xv * (double)w0.y;
      acc[2] += (double)xv * (double)w0.z;
      acc[3] += (double)xv * (double)w0.w;
      acc[4] += (double)xv * (double)w1.x;
      acc[5] += (double)xv * (double)w1.y;
      acc[6] += (double)xv * (double)w1.z;
      acc[7] += (double)xv * (double)w1.w;
    }
#pragma unroll
    for (int e = 0; e < E_; e++)
      for (int s = 32; s > 0; s >>= 1) acc[e] += __shfl_xor(acc[e], s);
    if (lane == 0) {
      double s[E_], m = -1e300;
      for (int e = 0; e < E_; e++) { s[e] = acc[e] + (double)br[e]; if (s[e] > m) m = s[e]; }
      double pe[E_], sum = 0.0;
      for (int e = 0; e < E_; e++) { pe[e] = exp(s[e] - m); sum += pe[e]; }
      double pr[E_], bb[E_];
      for (int e = 0; e < E_; e++) { pr[e] = pe[e] / sum; bb[e] = pr[e] + (double)bbuf[e]; }
      int e0 = 0;
      for (int e = 1; e < E_; e++) if (bb[e] > bb[e0]) e0 = e;
      int e1 = (e0 == 0) ? 1 : 0;
      for (int e = 0; e < E_; e++) if (e != e0 && bb[e] > bb[e1]) e1 = e;
      int a0 = 0;
      for (int e = 1; e < E_; e++) if (pr[e] > pr[a0]) a0 = e;
      int a1 = (a0 == 0) ? 1 : 0;
      for (int e = 0; e < E_; e++) if (e != a0 && pr[e] > pr[a1]) a1 = e;
      double iv = 1.0 / (pr[a0] + pr[a1]);
      te[t * 2] = e0; te[t * 2 + 1] = e1;
      tw[t * 2] = (float)(pr[a0] * iv); tw[t * 2 + 1] = (float)(pr[a1] * iv);
      atomicAdd(&cnt[e0], 1); atomicAdd(&cnt[e1], 1);
    }
    return;
  }
  if (bid < 4096) {
    int tcb = bid - 2048;
    if (tcb < VMBLK) {                    // folded init (disjoint from router)
      int i = tcb * 256 + threadIdx.x;
      if (i < VCAP) { tok[i] = -1; wl[i] = 0.f; v2c[i] = -1; }
    }
    transcvt_tile4(W1, W1T, 1024, 4096, tcb, tb);
    return;
  }
  transcvt_tile4(W2, W2T, 4096, 1024, bid - 4096, tb);
}

// ---------------- offsets: 256-padded virtual + compact prefix --------------
__global__ void k_offsets(const int* cnt, int* off, int* coff) {
  if (threadIdx.x == 0 && blockIdx.x == 0) {
    int o = 0, c = 0;
    for (int e = 0; e < E_; e++) {
      off[e] = o; coff[e] = c;
      o += ((cnt[e] + 255) >> 8) << 8;
      c += cnt[e];
    }
    off[E_] = o; coff[E_] = c;
  }
}

// ---------------- build token lists -----------------------------------------
__global__ void k_build(const int* __restrict__ te, const float* __restrict__ tw,
                        const int* __restrict__ off, const int* __restrict__ coff,
                        int* cur, int* tok, float* wl, int* v2c, int* ctok) {
  int t = blockIdx.x * 256 + threadIdx.x;
  if (t >= NTOK) return;
#pragma unroll
  for (int s = 0; s < 2; s++) {
    int e = te[t * 2 + s];
    int slot = atomicAdd(&cur[e], 1);
    int vp = off[e] + slot;
    int cp = coff[e] + slot;
    tok[vp] = t; wl[vp] = tw[t * 2 + s]; v2c[vp] = cp; ctok[cp] = t;
  }
}

// ---------------- gather x rows -> bf16 compact (+ fused out-zeroing) --------
__global__ __launch_bounds__(256) void k_gather(const float* __restrict__ x,
                                                const int* __restrict__ ctok,
                                                ushort* __restrict__ Xg,
                                                float* __restrict__ out) {
  int gid = blockIdx.x * 256 + threadIdx.x;
  if (gid < NTOK * H_ / 4) {
    float4 z; z.x = 0.f; z.y = 0.f; z.z = 0.f; z.w = 0.f;
    ((float4*)out)[gid] = z;
  }
  int row = blockIdx.x;
  int t = ctok[row];
  const float4* src = (const float4*)(x + (size_t)t * H_);
  ushort4* dst = (ushort4*)(Xg + (size_t)row * H_);
  int i = threadIdx.x;
  float4 v = src[i];
  ushort4 o; o.x = f2bf(v.x); o.y = f2bf(v.y); o.z = f2bf(v.z); o.w = f2bf(v.w);
  dst[i] = o;
}

// ---------------- 256x256x64 GEMM, m201-style phase ordering -----------------
// R7's verified chassis (macros/swizzle/addressing/epilogue refcheck'd) with
// the §5 template's per-phase ORDER, untested in R6-R9:
//   {ds_reads issued; stage issued; BAR; lgkm(0); setprio MFMA; BAR}
// Reads are in flight ACROSS the barrier (arrival skew absorbs LDS latency);
// MFMA follows immediately. 4 phases/K-tile (quadrants m0-3xn01 / m4-7xn01 /
// m4-7xn23 / m0-3xn23). Depth-1 prefetch: all 8 stage-issues of T+1 in
// phases 0-1 (into the OTHER buffer - race-free), single vmcnt(0) at tile
// boundary (~3 phases of cover for the youngest load).
// MODE 0: h1[v2c[row]] = gelu(A@B + b1[e]).  MODE 1: atomicAdd into Out.
template <int MODE>
__global__ __launch_bounds__(512) void k_gemm(const ushort* __restrict__ A,
                                              const ushort* __restrict__ BT,
                                              const float* __restrict__ bias,
                                              ushort* __restrict__ h1,
                                              float* __restrict__ Out,
                                              const int* __restrict__ off,
                                              const int* __restrict__ v2c,
                                              const int* __restrict__ tok,
                                              const float* __restrict__ wl,
                                              int K, int N) {
  extern __shared__ char lds[];
  // ---- raster: one ne per XCD chunk, m fastest (B panel L2-resident) ----
  int nwg = gridDim.x;             // 1152 (MODE0) or 576 (MODE1), div by 8
  int cpx = nwg >> 3;
  int bid = blockIdx.x;
  int lid = (bid & 7) * cpx + (bid >> 3);
  int ne = lid / VMBLK, m = lid % VMBLK;
  int row0 = m << 8;
  if (row0 >= off[E_]) return;
  int e = 0;
  while (off[e + 1] <= row0) e++;
  int n0, k0, nk;
  if (MODE == 0) { n0 = ne << 8; k0 = 0; nk = K >> 6; }
  else           { n0 = (ne & 3) << 8; k0 = (ne >> 2) * (K >> 1); nk = K >> 7; }
  const ushort* Bp = BT + (size_t)e * (size_t)N * (size_t)K;

  int tid = threadIdx.x, lane = tid & 63, w = tid >> 6;
  int wr = w >> 2, wc = w & 3;     // 2 M-halves x 4 N-quarters

  f32x4 acc[8][4];
#pragma unroll
  for (int mm = 0; mm < 8; mm++)
#pragma unroll
    for (int nn = 0; nn < 4; nn++) acc[mm][nn] = (f32x4){0.f, 0.f, 0.f, 0.f};

  // ---- staging addressing: unit = 64 rows x 128 B = 8 KB; thread = 16 B ----
  int urow = (w << 3) + (lane >> 3);        // 0..63 row within unit
  int schunk = (lane & 7) ^ (lane >> 3);    // pre-swizzled source chunk
  const char *aS0, *aS1, *aS2, *aS3, *bS0, *bS1, *bS2, *bS3;
  {
    int v0 = v2c[row0 + 0 * 64 + urow];   if (v0 < 0) v0 = 0;
    int v1 = v2c[row0 + 1 * 64 + urow];   if (v1 < 0) v1 = 0;
    int v2 = v2c[row0 + 2 * 64 + urow];   if (v2 < 0) v2 = 0;
    int v3 = v2c[row0 + 3 * 64 + urow];   if (v3 < 0) v3 = 0;
    size_t kb = (size_t)k0 * 2 + (size_t)schunk * 16;
    aS0 = (const char*)(A + (size_t)v0 * K) + kb;
    aS1 = (const char*)(A + (size_t)v1 * K) + kb;
    aS2 = (const char*)(A + (size_t)v2 * K) + kb;
    aS3 = (const char*)(A + (size_t)v3 * K) + kb;
    bS0 = (const char*)(Bp + (size_t)(n0 + 0 * 64 + urow) * K) + kb;
    bS1 = (const char*)(Bp + (size_t)(n0 + 1 * 64 + urow) * K) + kb;
    bS2 = (const char*)(Bp + (size_t)(n0 + 2 * 64 + urow) * K) + kb;
    bS3 = (const char*)(Bp + (size_t)(n0 + 3 * 64 + urow) * K) + kb;
  }

  int fr = lane & 15, fq = lane >> 4;
  int frs = fr & 7;

  short8 af_[4][2], bf_[2][2];

#define STG_A(u, tt, bbuf) glds16(aS##u + (size_t)(tt) * 128, lds + (bbuf) * 65536 + (u) * 8192 + (w << 10))
#define STG_B(u, tt, bbuf) glds16(bS##u + (size_t)(tt) * 128, lds + (bbuf) * 65536 + 32768 + (u) * 8192 + (w << 10))

#define RDA(mmq, bbuf) do {                                                  \
    const ushort* LA_ = (const ushort*)(lds + (bbuf) * 65536);               \
    _Pragma("unroll")                                                        \
    for (int i = 0; i < 4; ++i)                                              \
      _Pragma("unroll")                                                      \
      for (int ks = 0; ks < 2; ++ks)                                         \
        af_[i][ks] = *(const short8*)&LA_[((wr << 7) + ((mmq) + i) * 16 + fr) * 64 + (((ks << 2) + fq) ^ frs) * 8]; \
  } while (0)

#define RDB(nnq, bbuf) do {                                                  \
    const ushort* LB_ = (const ushort*)(lds + (bbuf) * 65536 + 32768);       \
    _Pragma("unroll")                                                        \
    for (int i = 0; i < 2; ++i)                                              \
      _Pragma("unroll")                                                      \
      for (int ks = 0; ks < 2; ++ks)                                         \
        bf_[i][ks] = *(const short8*)&LB_[((wc << 6) + ((nnq) + i) * 16 + fr) * 64 + (((ks << 2) + fq) ^ frs) * 8]; \
  } while (0)

#define MMQ(mmq, nnq) do {                                                   \
    __builtin_amdgcn_s_setprio(1);                                           \
    _Pragma("unroll")                                                        \
    for (int i = 0; i < 4; ++i)                                              \
      _Pragma("unroll")                                                      \
      for (int jn = 0; jn < 2; ++jn)                                         \
        _Pragma("unroll")                                                    \
        for (int ks = 0; ks < 2; ++ks)                                       \
          acc[(mmq) + i][(nnq) + jn] = __builtin_amdgcn_mfma_f32_16x16x32_bf16(af_[i][ks], bf_[jn][ks], acc[(mmq) + i][(nnq) + jn], 0, 0, 0); \
    __builtin_amdgcn_s_setprio(0);                                           \
  } while (0)

#define FENCE() __builtin_amdgcn_sched_barrier(0)
#define BAR()   __builtin_amdgcn_s_barrier()
#define WLGKM() asm volatile("s_waitcnt lgkmcnt(0)" ::: "memory")
#define WVM0()  asm volatile("s_waitcnt vmcnt(0)" ::: "memory")

  // ---- prologue: stage tile 0 -> buf 0, drain, sync ----
  STG_B(0, 0, 0); STG_B(1, 0, 0); STG_B(2, 0, 0); STG_B(3, 0, 0);
  STG_A(0, 0, 0); STG_A(1, 0, 0); STG_A(2, 0, 0); STG_A(3, 0, 0);
  WVM0();
  BAR(); FENCE();

  for (int T = 0; T < nk; ++T) {
    int b = T & 1, nb = b ^ 1;
    bool pre = (T + 1 < nk);
    // ---- phase 0: reads(af0-3, bf01) + stage B(T+1); BAR; wait; MFMA; BAR
    RDA(0, b); RDB(0, b);
    if (pre) { STG_B(0, T + 1, nb); STG_B(1, T + 1, nb);
               STG_B(2, T + 1, nb); STG_B(3, T + 1, nb); }
    BAR(); WLGKM(); FENCE();
    MMQ(0, 0);
    BAR();
    // ---- phase 1: reads(af4-7) + stage A(T+1)
    RDA(4, b);
    if (pre) { STG_A(0, T + 1, nb); STG_A(1, T + 1, nb);
               STG_A(2, T + 1, nb); STG_A(3, T + 1, nb); }
    BAR(); WLGKM(); FENCE();
    MMQ(4, 0);
    BAR();
    // ---- phase 2: reads(bf23)
    RDB(2, b);
    BAR(); WLGKM(); FENCE();
    MMQ(4, 2);
    BAR();
    // ---- phase 3: reads(af0-3)
    RDA(0, b);
    BAR(); WLGKM(); FENCE();
    MMQ(0, 2);
    FENCE();
    if (pre) WVM0();                 // T+1 landed (youngest issue ~3 phases old)
    BAR(); FENCE();
  }
#undef STG_A
#undef STG_B
#undef RDA
#undef RDB
#undef MMQ
#undef FENCE
#undef BAR
#undef WLGKM
#undef WVM0

  // ---- epilogue ----
  const float* bp = bias + (size_t)e * N;
  int cb = n0 + (wc << 6);
  if (MODE == 0) {
#pragma unroll
    for (int mm = 0; mm < 8; mm++) {
#pragma unroll
      for (int j = 0; j < 4; j++) {
        int vr = row0 + (wr << 7) + mm * 16 + (fq << 2) + j;
        int cr = v2c[vr];
        if (cr < 0) continue;
        ushort* hp = h1 + (size_t)cr * N + cb;
#pragma unroll
        for (int nn = 0; nn < 4; nn++) {
          float v = acc[mm][nn][j] + bp[cb + nn * 16 + fr];
          hp[nn * 16 + fr] = f2bf(gelu_t(v));
        }
      }
    }
  } else {
    bool addb = (k0 == 0);
#pragma unroll
    for (int mm = 0; mm < 8; mm++) {
#pragma unroll
      for (int j = 0; j < 4; j++) {
        int vr = row0 + (wr << 7) + mm * 16 + (fq << 2) + j;
        int t2 = tok[vr];
        if (t2 < 0) continue;
        float wgt = wl[vr];
#pragma unroll
        for (int nn = 0; nn < 4; nn++) {
          int c = cb + nn * 16 + fr;
          float v = acc[mm][nn][j] + (addb ? bp[c] : 0.f);
          atomicAdd(&Out[(size_t)t2 * (size_t)N + c], wgt * v);
        }
      }
    }
  }
}

extern "C" void kernel_launch(void* const* d_in, const int* in_sizes, int n_in,
                              void* d_out, int out_size, void* d_ws, size_t ws_size,
                              hipStream_t stream) {
  (void)in_sizes; (void)n_in; (void)out_size; (void)ws_size;
  const float* x    = (const float*)d_in[0];
  const float* bbuf = (const float*)d_in[1];
  const float* Wr   = (const float*)d_in[2];
  const float* br   = (const float*)d_in[3];
  const float* W1   = (const float*)d_in[4];
  const float* b1   = (const float*)d_in[5];
  const float* W2   = (const float*)d_in[6];
  const float* b2   = (const float*)d_in[7];
  float* out = (float*)d_out;

  char* ws = (char*)d_ws;
  ushort* W1T = (ushort*)ws;                          // [E][F][H] bf16  64 MB
  ushort* W2T = (ushort*)(ws + 67108864);             // [E][H][F] bf16  64 MB
  ushort* Xg  = (ushort*)(ws + 134217728);            // [NCOMP][H] bf16 32 MB
  ushort* h1  = (ushort*)(ws + 167772160);            // [NCOMP][F] bf16 128 MB
  char* meta  = ws + 301989888;
  int*   cnt  = (int*)(meta);
  int*   off  = (int*)(meta + 64);
  int*   coff = (int*)(meta + 128);
  int*   cur  = (int*)(meta + 192);
  int*   te   = (int*)(meta + 256);                   // [NTOK*2]
  float* tw   = (float*)(meta + 65792);               // [NTOK*2]
  int*   tok  = (int*)(meta + 131328);                // [VCAP]
  float* wl   = (float*)(meta + 205056);              // [VCAP]
  int*   v2c  = (int*)(meta + 278784);                // [VCAP]
  int*   ctok = (int*)(meta + 352512);                // [NCOMP]

  hipFuncSetAttribute((const void*)&k_gemm<0>,
                      hipFuncAttributeMaxDynamicSharedMemorySize, 131072);
  hipFuncSetAttribute((const void*)&k_gemm<1>,
                      hipFuncAttributeMaxDynamicSharedMemorySize, 131072);

  // single small memset: cnt/off/coff/cur (must precede router atomics)
  hipMemsetAsync(meta, 0, 256, stream);

  // router (2048) + W1T wide (2048) + W2T wide (2048); init folded
  k_prep2<<<6144, 256, 0, stream>>>(W1, W1T, W2, W2T, x, Wr, br, bbuf,
                                    cnt, te, tw, tok, wl, v2c);
  k_offsets<<<1, 64, 0, stream>>>(cnt, off, coff);
  k_build<<<NTOK / 256, 256, 0, stream>>>(te, tw, off, coff, cur, tok, wl, v2c, ctok);
  k_gather<<<NCOMP, 256, 0, stream>>>(x, ctok, Xg, out);
  // GEMM1: 16 n-tiles x 72 m-tiles = 1152 blocks, K=1024 (16 K-tiles)
  k_gemm<0><<<16 * VMBLK, 512, 131072, stream>>>(Xg, W1T, b1, h1, nullptr,
                                                 off, v2c, nullptr, nullptr,
                                                 H_, F_);
  // GEMM2: (4 n-tiles x 2 K-splits) x 72 = 576 blocks, 32 K-tiles/split
  k_gemm<1><<<8 * VMBLK, 512, 131072, stream>>>(h1, W2T, b2, nullptr, out,
                                                off, v2c, tok, wl,
                                                F_, H_);
}

// Round 20
// 867.299 us; speedup vs baseline: 1.1170x; 1.1170x over previous
//
#include <hip/hip_runtime.h>
#include <stdint.h>

#define NTOK 8192
#define H_ 1024
#define F_ 4096
#define E_ 8
#define VCAP 18432      // 16384 slots + up to 8*256 padding (virtual rows)
#define VMBLK 72        // VCAP/256
#define MT 144          // VCAP/128 M-tiles for the 128-row GEMM rasters
#define NCOMP 16384     // compact rows (= NTOK * k exactly)
#define NWG1 4608       // GEMM1 logical grid (32 n-tiles x 144 m-tiles)

using f32x4  = __attribute__((ext_vector_type(4))) float;
using short8 = __attribute__((ext_vector_type(8))) short;

typedef __attribute__((address_space(1))) const uint32_t gu32;
typedef __attribute__((address_space(3))) uint32_t lu32;

__device__ __forceinline__ void glds16(const void* g, void* l) {
  __builtin_amdgcn_global_load_lds((gu32*)g, (lu32*)l, 16, 0, 0);
}

__device__ __forceinline__ ushort f2bf(float f) {
  union { float f; uint32_t u; } v; v.f = f;
  uint32_t r = (v.u + 0x7FFFu + ((v.u >> 16) & 1u)) >> 16;
  return (ushort)r;
}

__device__ __forceinline__ float gelu_t(float x) {
  float u = 0.7978845608028654f * (x + 0.044715f * x * x * x);
  float e = exp2f(u * 2.885390081777927f);      // exp(2u)
  float th = 1.0f - 2.0f / (1.0f + e);
  return 0.5f * x * (1.0f + th);
}

// ---- wide transpose: one block does a 64-row x 256-col region (4 sub-tiles).
// All 16 float4 global reads issued upfront (1 KB contiguous per row across
// phases); 4 LDS phases amortize a single load latency. fp32 -> bf16.
__device__ __forceinline__ void transcvt_tile4(const float* __restrict__ W,
                                               ushort* __restrict__ WT,
                                               int R, int C, int t4,
                                               float (*tb)[65]) {
  int nxw = C >> 8;                         // wide tiles per row-band
  int per_e = (R >> 6) * nxw;
  int e = t4 / per_e, rem = t4 % per_e;
  int r0 = (rem / nxw) << 6, c0 = (rem % nxw) << 8;
  const float* Wp = W + (size_t)e * R * C;
  ushort* Tp = WT + (size_t)e * R * C;
  int tx = threadIdx.x & 15, ty = threadIdx.x >> 4;

  float4 v[4][4];
#pragma unroll
  for (int p = 0; p < 4; p++)
#pragma unroll
    for (int i = 0; i < 4; i++) {
      int lr = ty + i * 16;
      v[p][i] = *(const float4*)&Wp[(size_t)(r0 + lr) * C + c0 + p * 64 + tx * 4];
    }

#pragma unroll
  for (int p = 0; p < 4; p++) {
    __syncthreads();
#pragma unroll
    for (int i = 0; i < 4; i++) {
      int lr = ty + i * 16;
      tb[lr][tx * 4 + 0] = v[p][i].x; tb[lr][tx * 4 + 1] = v[p][i].y;
      tb[lr][tx * 4 + 2] = v[p][i].z; tb[lr][tx * 4 + 3] = v[p][i].w;
    }
    __syncthreads();
#pragma unroll
    for (int i = 0; i < 4; i++) {
      int lc = ty + i * 16;
      ushort4 o;
      o.x = f2bf(tb[tx * 4 + 0][lc]);
      o.y = f2bf(tb[tx * 4 + 1][lc]);
      o.z = f2bf(tb[tx * 4 + 2][lc]);
      o.w = f2bf(tb[tx * 4 + 3][lc]);
      *(ushort4*)&Tp[(size_t)(c0 + p * 64 + lc) * R + r0 + tx * 4] = o;
    }
  }
}

// ---- prep2: router (blocks 0..2047) + W1 wide-transpose (2048..4095) -------
// First VMBLK transpose blocks additionally init tok/wl/v2c (read only by
// later kernels). cnt/cur zeroed by a preceding 256-B memset.
__global__ __launch_bounds__(256) void k_prep2(const float* __restrict__ W1,
                                               ushort* __restrict__ W1T,
                                               const float* __restrict__ x,
                                               const float* __restrict__ Wr,
                                               const float* __restrict__ br,
                                               const float* __restrict__ bbuf,
                                               int* cnt, int* te, float* tw,
                                               int* tok, float* wl, int* v2c) {
  __shared__ float tb[64][65];
  int bid = blockIdx.x;
  if (bid < 2048) {                       // ---- router path ----
    int wid = threadIdx.x >> 6, lane = threadIdx.x & 63;
    int t = bid * 4 + wid;
    const float* xp = x + (size_t)t * H_;
    double acc[E_];
#pragma unroll
    for (int e = 0; e < E_; e++) acc[e] = 0.0;
    for (int j = lane; j < H_; j += 64) {
      float xv = xp[j];
      const float4 w0 = *(const float4*)&Wr[j * 8];
      const float4 w1 = *(const float4*)&Wr[j * 8 + 4];
      acc[0] += (double)xv * (double)w0.x;
      acc[1] += (double)xv * (double)w0.y;
      acc[2] += (double)xv * (double)w0.z;
      acc[3] += (double)xv * (double)w0.w;
      acc[4] += (double)xv * (double)w1.x;
      acc[5] += (double)xv * (double)w1.y;
      acc[6] += (double)xv * (double)w1.z;
      acc[7] += (double)xv * (double)w1.w;
    }
#pragma unroll
    for (int e = 0; e < E_; e++)
      for (int s = 32; s > 0; s >>= 1) acc[e] += __shfl_xor(acc[e], s);
    if (lane == 0) {
      double s[E_], m = -1e300;
      for (int e = 0; e < E_; e++) { s[e] = acc[e] + (double)br[e]; if (s[e] > m) m = s[e]; }
      double pe[E_], sum = 0.0;
      for (int e = 0; e < E_; e++) { pe[e] = exp(s[e] - m); sum += pe[e]; }
      double pr[E_], bb[E_];
      for (int e = 0; e < E_; e++) { pr[e] = pe[e] / sum; bb[e] = pr[e] + (double)bbuf[e]; }
      int e0 = 0;
      for (int e = 1; e < E_; e++) if (bb[e] > bb[e0]) e0 = e;
      int e1 = (e0 == 0) ? 1 : 0;
      for (int e = 0; e < E_; e++) if (e != e0 && bb[e] > bb[e1]) e1 = e;
      int a0 = 0;
      for (int e = 1; e < E_; e++) if (pr[e] > pr[a0]) a0 = e;
      int a1 = (a0 == 0) ? 1 : 0;
      for (int e = 0; e < E_; e++) if (e != a0 && pr[e] > pr[a1]) a1 = e;
      double iv = 1.0 / (pr[a0] + pr[a1]);
      te[t * 2] = e0; te[t * 2 + 1] = e1;
      tw[t * 2] = (float)(pr[a0] * iv); tw[t * 2 + 1] = (float)(pr[a1] * iv);
      atomicAdd(&cnt[e0], 1); atomicAdd(&cnt[e1], 1);
    }
    return;
  }
  int tcb = bid - 2048;                   // 0..2047
  if (tcb < VMBLK) {                      // folded init (disjoint from router)
    int i = tcb * 256 + threadIdx.x;
    if (i < VCAP) { tok[i] = -1; wl[i] = 0.f; v2c[i] = -1; }
  }
  transcvt_tile4(W1, W1T, 1024, 4096, tcb, tb);
}

// ---------------- offsets: 256-padded virtual + compact prefix --------------
__global__ void k_offsets(const int* cnt, int* off, int* coff) {
  if (threadIdx.x == 0 && blockIdx.x == 0) {
    int o = 0, c = 0;
    for (int e = 0; e < E_; e++) {
      off[e] = o; coff[e] = c;
      o += ((cnt[e] + 255) >> 8) << 8;
      c += cnt[e];
    }
    off[E_] = o; coff[E_] = c;
  }
}

// ---------------- build token lists -----------------------------------------
__global__ void k_build(const int* __restrict__ te, const float* __restrict__ tw,
                        const int* __restrict__ off, const int* __restrict__ coff,
                        int* cur, int* tok, float* wl, int* v2c, int* ctok) {
  int t = blockIdx.x * 256 + threadIdx.x;
  if (t >= NTOK) return;
#pragma unroll
  for (int s = 0; s < 2; s++) {
    int e = te[t * 2 + s];
    int slot = atomicAdd(&cur[e], 1);
    int vp = off[e] + slot;
    int cp = coff[e] + slot;
    tok[vp] = t; wl[vp] = tw[t * 2 + s]; v2c[vp] = cp; ctok[cp] = t;
  }
}

// ---------------- gather x rows -> bf16 compact (+ fused out-zeroing) --------
__global__ __launch_bounds__(256) void k_gather(const float* __restrict__ x,
                                                const int* __restrict__ ctok,
                                                ushort* __restrict__ Xg,
                                                float* __restrict__ out) {
  int gid = blockIdx.x * 256 + threadIdx.x;
  if (gid < NTOK * H_ / 4) {
    float4 z; z.x = 0.f; z.y = 0.f; z.z = 0.f; z.w = 0.f;
    ((float4*)out)[gid] = z;
  }
  int row = blockIdx.x;
  int t = ctok[row];
  const float4* src = (const float4*)(x + (size_t)t * H_);
  ushort4* dst = (ushort4*)(Xg + (size_t)row * H_);
  int i = threadIdx.x;
  float4 v = src[i];
  ushort4 o; o.x = f2bf(v.x); o.y = f2bf(v.y); o.z = f2bf(v.z); o.w = f2bf(v.w);
  dst[i] = o;
}

// ---- fused GEMM1 + W2 wide-transpose: 6656 blocks = 512 x (9 gemm + 4 tc) --
// GEMM1 = R13/R15's exact 128x128x64, (256,3), verified swizzle, XCD raster.
// Transpose blocks co-run on the memory pipe while GEMM blocks use MFMA/LDS.
__global__ __launch_bounds__(256, 3) void k_gemm1f(const ushort* __restrict__ A,
                                                   const ushort* __restrict__ BT,
                                                   const float* __restrict__ bias,
                                                   ushort* __restrict__ h1,
                                                   const int* __restrict__ off,
                                                   const int* __restrict__ v2c,
                                                   const float* __restrict__ W2,
                                                   ushort* __restrict__ W2T) {
  __shared__ __align__(16) char smem[32768];
  int g = blockIdx.x / 13, idx = blockIdx.x % 13;
  if (idx >= 9) {                         // ---- W2 wide-transpose path ----
    float (*tb)[65] = (float(*)[65])smem;
    transcvt_tile4(W2, W2T, 4096, 1024, g * 4 + (idx - 9), tb);
    return;
  }
  // ---- GEMM1 path ----
  const int K = H_, N = F_;
  ushort* As = (ushort*)smem;             // [128*64]
  ushort* Bs = (ushort*)(smem + 16384);   // [128*64]
  int gid = g * 9 + idx;                  // 0..4607
  int cpx = NWG1 >> 3;
  int lid = (gid & 7) * cpx + (gid >> 3);
  int ng = lid / (MT * 8), r = lid % (MT * 8);
  int m = r >> 3;
  int ne = (ng << 3) + (r & 7);
  int row0 = m << 7;
  if (row0 >= off[E_]) return;
  int e = 0;
  while (off[e + 1] <= row0) e++;
  int n0 = ne << 7, nk = K >> 6;
  const ushort* Bp = BT + (size_t)e * (size_t)N * (size_t)K;

  int lane = threadIdx.x & 63, w = threadIdx.x >> 6;
  int wr = w >> 1, wc = w & 1;

  f32x4 acc[4][4];
#pragma unroll
  for (int mm = 0; mm < 4; mm++)
#pragma unroll
    for (int nn = 0; nn < 4; nn++) acc[mm][nn] = (f32x4){0.f, 0.f, 0.f, 0.f};

  int urow = (w << 3) + (lane >> 3);
  int sc = (lane & 7) ^ (urow & 7);
  const char *aP0, *aP1, *aP2, *aP3, *bP0, *bP1, *bP2, *bP3;
  {
    size_t kb = (size_t)sc * 16;
    int c0 = v2c[row0 + 0 * 32 + urow];  if (c0 < 0) c0 = 0;
    int c1 = v2c[row0 + 1 * 32 + urow];  if (c1 < 0) c1 = 0;
    int c2 = v2c[row0 + 2 * 32 + urow];  if (c2 < 0) c2 = 0;
    int c3 = v2c[row0 + 3 * 32 + urow];  if (c3 < 0) c3 = 0;
    aP0 = (const char*)(A + (size_t)c0 * K) + kb;
    aP1 = (const char*)(A + (size_t)c1 * K) + kb;
    aP2 = (const char*)(A + (size_t)c2 * K) + kb;
    aP3 = (const char*)(A + (size_t)c3 * K) + kb;
    bP0 = (const char*)(Bp + (size_t)(n0 + 0 * 32 + urow) * K) + kb;
    bP1 = (const char*)(Bp + (size_t)(n0 + 1 * 32 + urow) * K) + kb;
    bP2 = (const char*)(Bp + (size_t)(n0 + 2 * 32 + urow) * K) + kb;
    bP3 = (const char*)(Bp + (size_t)(n0 + 3 * 32 + urow) * K) + kb;
  }

  int fr = lane & 15, fq = lane >> 4;
  int frs = fr & 7;

  for (int kk = 0; kk < nk; ++kk) {
    size_t kbo = (size_t)kk * 128;
    if (kk) __syncthreads();
    glds16(aP0 + kbo, (char*)As + 0 * 4096 + (w << 10));
    glds16(bP0 + kbo, (char*)Bs + 0 * 4096 + (w << 10));
    glds16(aP1 + kbo, (char*)As + 1 * 4096 + (w << 10));
    glds16(bP1 + kbo, (char*)Bs + 1 * 4096 + (w << 10));
    glds16(aP2 + kbo, (char*)As + 2 * 4096 + (w << 10));
    glds16(bP2 + kbo, (char*)Bs + 2 * 4096 + (w << 10));
    glds16(aP3 + kbo, (char*)As + 3 * 4096 + (w << 10));
    glds16(bP3 + kbo, (char*)Bs + 3 * 4096 + (w << 10));
    __syncthreads();
#pragma unroll
    for (int ks = 0; ks < 2; ++ks) {
      short8 af[4], bf[4];
      int kc = (((ks << 2) + fq) ^ frs) << 3;
#pragma unroll
      for (int i = 0; i < 4; ++i)
        af[i] = *(const short8*)&As[((wr << 6) + i * 16 + fr) * 64 + kc];
#pragma unroll
      for (int i = 0; i < 4; ++i)
        bf[i] = *(const short8*)&Bs[((wc << 6) + i * 16 + fr) * 64 + kc];
#pragma unroll
      for (int mm = 0; mm < 4; ++mm)
#pragma unroll
        for (int nn = 0; nn < 4; ++nn)
          acc[mm][nn] = __builtin_amdgcn_mfma_f32_16x16x32_bf16(af[mm], bf[nn], acc[mm][nn], 0, 0, 0);
    }
  }

  const float* bp = bias + (size_t)e * N;
  int cb = n0 + (wc << 6);
#pragma unroll
  for (int mm = 0; mm < 4; mm++) {
#pragma unroll
    for (int j = 0; j < 4; j++) {
      int vr = row0 + (wr << 6) + mm * 16 + (fq << 2) + j;
      int cr = v2c[vr];
      if (cr < 0) continue;
      ushort* hp = h1 + (size_t)cr * N + cb;
#pragma unroll
      for (int nn = 0; nn < 4; nn++) {
        float v = acc[mm][nn][j] + bp[cb + nn * 16 + fr];
        hp[nn * 16 + fr] = f2bf(gelu_t(v));
      }
    }
  }
}

// ---------------- GEMM2: 128x128x64, split-K 2, atomic combine (R15 exact) ---
__global__ __launch_bounds__(256, 3) void k_gemm2(const ushort* __restrict__ A,
                                                  const ushort* __restrict__ BT,
                                                  const float* __restrict__ bias,
                                                  float* __restrict__ Out,
                                                  const int* __restrict__ off,
                                                  const int* __restrict__ v2c,
                                                  const int* __restrict__ tok,
                                                  const float* __restrict__ wl) {
  __shared__ __align__(16) ushort As[128 * 64];
  __shared__ __align__(16) ushort Bs[128 * 64];
  const int K = F_, N = H_;
  int nwg = gridDim.x;
  int cpx = nwg >> 3;
  int bid = blockIdx.x;
  int lid = (bid & 7) * cpx + (bid >> 3);
  int ng = lid / (MT * 8), r = lid % (MT * 8);
  int m = r >> 3;
  int ne = (ng << 3) + (r & 7);
  int row0 = m << 7;
  if (row0 >= off[E_]) return;
  int e = 0;
  while (off[e + 1] <= row0) e++;
  int n0 = (ne & 7) << 7, k0 = (ne >> 3) * (K >> 1), nk = K >> 7;
  const ushort* Bp = BT + (size_t)e * (size_t)N * (size_t)K;

  int lane = threadIdx.x & 63, w = threadIdx.x >> 6;
  int wr = w >> 1, wc = w & 1;

  f32x4 acc[4][4];
#pragma unroll
  for (int mm = 0; mm < 4; mm++)
#pragma unroll
    for (int nn = 0; nn < 4; nn++) acc[mm][nn] = (f32x4){0.f, 0.f, 0.f, 0.f};

  int urow = (w << 3) + (lane >> 3);
  int sc = (lane & 7) ^ (urow & 7);
  const char *aP0, *aP1, *aP2, *aP3, *bP0, *bP1, *bP2, *bP3;
  {
    size_t kb = (size_t)k0 * 2 + (size_t)sc * 16;
    int c0 = v2c[row0 + 0 * 32 + urow];  if (c0 < 0) c0 = 0;
    int c1 = v2c[row0 + 1 * 32 + urow];  if (c1 < 0) c1 = 0;
    int c2 = v2c[row0 + 2 * 32 + urow];  if (c2 < 0) c2 = 0;
    int c3 = v2c[row0 + 3 * 32 + urow];  if (c3 < 0) c3 = 0;
    aP0 = (const char*)(A + (size_t)c0 * K) + kb;
    aP1 = (const char*)(A + (size_t)c1 * K) + kb;
    aP2 = (const char*)(A + (size_t)c2 * K) + kb;
    aP3 = (const char*)(A + (size_t)c3 * K) + kb;
    bP0 = (const char*)(Bp + (size_t)(n0 + 0 * 32 + urow) * K) + kb;
    bP1 = (const char*)(Bp + (size_t)(n0 + 1 * 32 + urow) * K) + kb;
    bP2 = (const char*)(Bp + (size_t)(n0 + 2 * 32 + urow) * K) + kb;
    bP3 = (const char*)(Bp + (size_t)(n0 + 3 * 32 + urow) * K) + kb;
  }

  int fr = lane & 15, fq = lane >> 4;
  int frs = fr & 7;

  for (int kk = 0; kk < nk; ++kk) {
    size_t kbo = (size_t)kk * 128;
    if (kk) __syncthreads();
    glds16(aP0 + kbo, (char*)As + 0 * 4096 + (w << 10));
    glds16(bP0 + kbo, (char*)Bs + 0 * 4096 + (w << 10));
    glds16(aP1 + kbo, (char*)As + 1 * 4096 + (w << 10));
    glds16(bP1 + kbo, (char*)Bs + 1 * 4096 + (w << 10));
    glds16(aP2 + kbo, (char*)As + 2 * 4096 + (w << 10));
    glds16(bP2 + kbo, (char*)Bs + 2 * 4096 + (w << 10));
    glds16(aP3 + kbo, (char*)As + 3 * 4096 + (w << 10));
    glds16(bP3 + kbo, (char*)Bs + 3 * 4096 + (w << 10));
    __syncthreads();
#pragma unroll
    for (int ks = 0; ks < 2; ++ks) {
      short8 af[4], bf[4];
      int kc = (((ks << 2) + fq) ^ frs) << 3;
#pragma unroll
      for (int i = 0; i < 4; ++i)
        af[i] = *(const short8*)&As[((wr << 6) + i * 16 + fr) * 64 + kc];
#pragma unroll
      for (int i = 0; i < 4; ++i)
        bf[i] = *(const short8*)&Bs[((wc << 6) + i * 16 + fr) * 64 + kc];
#pragma unroll
      for (int mm = 0; mm < 4; ++mm)
#pragma unroll
        for (int nn = 0; nn < 4; ++nn)
          acc[mm][nn] = __builtin_amdgcn_mfma_f32_16x16x32_bf16(af[mm], bf[nn], acc[mm][nn], 0, 0, 0);
    }
  }

  const float* bp = bias + (size_t)e * N;
  int cb = n0 + (wc << 6);
  bool addb = (k0 == 0);
#pragma unroll
  for (int mm = 0; mm < 4; mm++) {
#pragma unroll
    for (int j = 0; j < 4; j++) {
      int vr = row0 + (wr << 6) + mm * 16 + (fq << 2) + j;
      int t2 = tok[vr];
      if (t2 < 0) continue;
      float wgt = wl[vr];
#pragma unroll
      for (int nn = 0; nn < 4; nn++) {
        int c = cb + nn * 16 + fr;
        float v = acc[mm][nn][j] + (addb ? bp[c] : 0.f);
        atomicAdd(&Out[(size_t)t2 * (size_t)N + c], wgt * v);
      }
    }
  }
}

extern "C" void kernel_launch(void* const* d_in, const int* in_sizes, int n_in,
                              void* d_out, int out_size, void* d_ws, size_t ws_size,
                              hipStream_t stream) {
  (void)in_sizes; (void)n_in; (void)out_size; (void)ws_size;
  const float* x    = (const float*)d_in[0];
  const float* bbuf = (const float*)d_in[1];
  const float* Wr   = (const float*)d_in[2];
  const float* br   = (const float*)d_in[3];
  const float* W1   = (const float*)d_in[4];
  const float* b1   = (const float*)d_in[5];
  const float* W2   = (const float*)d_in[6];
  const float* b2   = (const float*)d_in[7];
  float* out = (float*)d_out;

  char* ws = (char*)d_ws;
  ushort* W1T = (ushort*)ws;                          // [E][F][H] bf16  64 MB
  ushort* W2T = (ushort*)(ws + 67108864);             // [E][H][F] bf16  64 MB
  ushort* Xg  = (ushort*)(ws + 134217728);            // [NCOMP][H] bf16 32 MB
  ushort* h1  = (ushort*)(ws + 167772160);            // [NCOMP][F] bf16 128 MB
  char* meta  = ws + 301989888;
  int*   cnt  = (int*)(meta);
  int*   off  = (int*)(meta + 64);
  int*   coff = (int*)(meta + 128);
  int*   cur  = (int*)(meta + 192);
  int*   te   = (int*)(meta + 256);                   // [NTOK*2]
  float* tw   = (float*)(meta + 65792);               // [NTOK*2]
  int*   tok  = (int*)(meta + 131328);                // [VCAP]
  float* wl   = (float*)(meta + 205056);              // [VCAP]
  int*   v2c  = (int*)(meta + 278784);                // [VCAP]
  int*   ctok = (int*)(meta + 352512);                // [NCOMP]

  // single small memset: cnt/off/coff/cur (must precede router atomics)
  hipMemsetAsync(meta, 0, 256, stream);

  // router (2048 blocks) + W1 wide-transpose (2048 blocks); init folded
  k_prep2<<<4096, 256, 0, stream>>>(W1, W1T, x, Wr, br, bbuf, cnt, te, tw,
                                    tok, wl, v2c);
  k_offsets<<<1, 64, 0, stream>>>(cnt, off, coff);
  k_build<<<NTOK / 256, 256, 0, stream>>>(te, tw, off, coff, cur, tok, wl, v2c, ctok);
  k_gather<<<NCOMP, 256, 0, stream>>>(x, ctok, Xg, out);
  // fused: GEMM1 (4608 logical) + W2 wide-transpose (2048 tiles), 6656 blocks
  k_gemm1f<<<6656, 256, 0, stream>>>(Xg, W1T, b1, h1, off, v2c, W2, W2T);
  // GEMM2: N=1024 (8 n-tiles) x split-K 2 -> 16*144 = 2304 blocks
  k_gemm2<<<16 * MT, 256, 0, stream>>>(h1, W2T, b2, out, off, v2c, tok, wl);
}